// Round 1
// baseline (240.438 us; speedup 1.0000x reference)
//
#include <hip/hip_runtime.h>

// Problem constants: B=4, C=64, H=256, W=512 (fp32)
constexpr int B = 4;
constexpr int C = 64;
constexpr int H = 256;
constexpr int W = 512;
constexpr int CH_PER_BLOCK = 16;                 // channels per block
constexpr int WAVES = 4;                        // 256 threads
constexpr int CH_PER_WAVE = CH_PER_BLOCK / WAVES; // 4

// Barrier-free design: each wave owns one (b,h) row slice and CH_PER_WAVE
// channels, staged through a wave-private LDS double buffer. No s_barrier
// anywhere -> no vmcnt(0) drains; stores stream, loads prefetch one channel
// ahead. Gathers are stride-1 across lanes (w = lane + 64*j) -> conflict-free.
__global__ __launch_bounds__(256) void spatial_warp_kernel(
    const float* __restrict__ input,   // [B,C,H,W]
    const float* __restrict__ disp,    // [B,1,H,W]
    float* __restrict__ out)           // [B,C,H,W]
{
    __shared__ float s_rows[WAVES][2][W];   // 16 KiB, wave-private double buffers

    const int t    = threadIdx.x;
    const int lane = t & 63;
    const int wid  = t >> 6;

    const int cg = blockIdx.x % (C / CH_PER_BLOCK);
    int rest     = blockIdx.x / (C / CH_PER_BLOCK);
    const int h  = rest % H;
    const int b  = rest / H;
    const int c0 = cg * CH_PER_BLOCK + wid * CH_PER_WAVE;

    const long long pix = ((long long)b * H + h) * (long long)W;

    // ---- per-lane warp params for w = lane + 64*j  (channel-invariant) ----
    // Exploit idx_b == idx_a+1 in-bounds: read the pair (row[i0], row[i0+1]).
    // ia == W-1 corner (wa=1 path) folded into weights: waf=0, wbf=msk, i0=W-2
    // so fb==row[W-1] carries the whole value. OOB folded into msk.
    float waf[8], wbf[8];
    int   addr0[8];                      // byte offset of pair base within a row
    const float* drow = disp + pix;
#pragma unroll
    for (int j = 0; j < 8; ++j) {
        const int w   = lane + 64 * j;
        const float d  = drow[w];
        const float ry = (float)w + d;
        const float ra = floorf(ry);
        const float wa = ra + 1.0f - ry;
        const float wb = ry - ra;
        const float msk = (ry >= 0.0f && ry <= (float)(W - 1)) ? 1.0f : 0.0f;
        const float iaf = fminf(fmaxf(ra, 0.0f), (float)(W - 1));
        const int   ia  = (int)iaf;
        const bool  hi  = (ia >= W - 1);
        const int   i0  = hi ? (W - 2) : ia;
        waf[j]   = hi ? 0.0f : msk * wa;
        wbf[j]   = hi ? msk  : msk * wb;
        addr0[j] = i0 * 4;
    }

    // ---- channel loop: prefetch c+1 into regs, stage c via LDS, no barriers ----
    const long long chStride = (long long)H * W;
    const float* grow = input + ((long long)(b * C + c0)) * chStride + pix % ((long long)H * W)
                        ;
    // (recompute cleanly to avoid confusion)
    grow = input + (((long long)b * C + c0) * H + h) * (long long)W;
    float* orow = out + (((long long)b * C + c0) * H + h) * (long long)W;

    // initial prefetch of channel c0 row: lane covers float4 idx {lane, lane+64}
    float4 v0 = reinterpret_cast<const float4*>(grow)[lane];
    float4 v1 = reinterpret_cast<const float4*>(grow)[64 + lane];

#pragma unroll
    for (int cc = 0; cc < CH_PER_WAVE; ++cc) {
        float* buf = &s_rows[wid][cc & 1][0];
        reinterpret_cast<float4*>(buf)[lane]      = v0;  // waits vmcnt on v0/v1 only
        reinterpret_cast<float4*>(buf)[64 + lane] = v1;  // (stores stay in flight)

        if (cc + 1 < CH_PER_WAVE) {
            const float* gnext = grow + (long long)(cc + 1) * chStride;
            v0 = reinterpret_cast<const float4*>(gnext)[lane];
            v1 = reinterpret_cast<const float4*>(gnext)[64 + lane];
        }

        // Wave-private LDS: DS ops of one wave complete in order; only need
        // the counter drained + a compiler ordering fence (no s_barrier).
        asm volatile("s_waitcnt lgkmcnt(0)" ::: "memory");

        float* op = orow + (long long)cc * chStride;
#pragma unroll
        for (int j = 0; j < 8; ++j) {
            const float fa = *reinterpret_cast<const float*>(
                reinterpret_cast<const char*>(buf) + addr0[j]);
            const float fb = *reinterpret_cast<const float*>(
                reinterpret_cast<const char*>(buf) + addr0[j] + 4);
            op[lane + 64 * j] = waf[j] * fa + wbf[j] * fb;   // stride-1 lanes: coalesced
        }
    }
}

extern "C" void kernel_launch(void* const* d_in, const int* in_sizes, int n_in,
                              void* d_out, int out_size, void* d_ws, size_t ws_size,
                              hipStream_t stream) {
    const float* input = (const float*)d_in[0];   // right_input [B,C,H,W]
    const float* disp  = (const float*)d_in[1];   // disparity_samples [B,1,H,W]
    float* outp = (float*)d_out;

    const int grid = B * H * (C / CH_PER_BLOCK);  // 4*256*4 = 4096 blocks
    spatial_warp_kernel<<<grid, 256, 0, stream>>>(input, disp, outp);
}

// Round 2
// 240.234 us; speedup vs baseline: 1.0008x; 1.0008x over previous
//
#include <hip/hip_runtime.h>

// Problem constants: B=4, C=64, H=256, W=512 (fp32)
constexpr int B = 4;
constexpr int C = 64;
constexpr int H = 256;
constexpr int W = 512;
constexpr int CPB = 16;                     // channels per block
constexpr long long HW = (long long)H * W;  // channel stride in floats

// No-LDS streaming gather. One thread per w (512-thread block = 8 waves),
// 16 channels fully unrolled: 32 independent global loads in flight per lane
// (128 B/lane MLP), then 16 fma+store. Zero barriers, zero LDS, no lgkm waits.
// Per-lane gather addresses are monotone (stride-1 for disp in [0,1)) so the
// coalescer merges them like regular loads. Weights/indices are channel-
// invariant: computed once per thread.
//   idx_b == idx_a+1 in-bounds; the ia==W-1 corner is folded into the weights
//   (waf=0, wbf=msk, i0=W-2) and OOB is folded into msk — no selects in the
//   data path.
__global__ __launch_bounds__(512) void spatial_warp_kernel(
    const float* __restrict__ input,   // [B,C,H,W]
    const float* __restrict__ disp,    // [B,1,H,W]
    float* __restrict__ out)           // [B,C,H,W]
{
    const int w    = threadIdx.x;                 // 0..511
    const int cg   = blockIdx.x & (C / CPB - 1);  // 4 channel groups
    const int rest = blockIdx.x >> 2;
    const int h    = rest & (H - 1);
    const int b    = rest >> 8;                   // H = 256

    const long long pix = ((long long)b * H + h) * (long long)W;

    // ---- per-thread warp params (channel-invariant) ----
    const float d   = disp[pix + w];
    const float ry  = (float)w + d;
    const float ra  = floorf(ry);
    const float wa  = ra + 1.0f - ry;
    const float wb  = ry - ra;
    const float msk = (ry >= 0.0f && ry <= (float)(W - 1)) ? 1.0f : 0.0f;
    const float iaf = fminf(fmaxf(ra, 0.0f), (float)(W - 1));
    const int   ia  = (int)iaf;
    const bool  hi  = (ia >= W - 1);
    const int   i0  = hi ? (W - 2) : ia;
    const float waf = hi ? 0.0f : msk * wa;
    const float wbf = hi ? msk  : msk * wb;

    const int c0 = cg * CPB;
    const float* p = input + (((long long)b * C + c0) * H + h) * (long long)W;
    float*       q = out   + (((long long)b * C + c0) * H + h) * (long long)W + w;

    // ---- issue all 32 loads, then compute+store ----
    float va[CPB], vb[CPB];
#pragma unroll
    for (int cc = 0; cc < CPB; ++cc) {
        const float* row = p + (long long)cc * HW;
        va[cc] = row[i0];
        vb[cc] = row[i0 + 1];
    }
#pragma unroll
    for (int cc = 0; cc < CPB; ++cc) {
        __builtin_nontemporal_store(waf * va[cc] + wbf * vb[cc],
                                    q + (long long)cc * HW);
    }
}

extern "C" void kernel_launch(void* const* d_in, const int* in_sizes, int n_in,
                              void* d_out, int out_size, void* d_ws, size_t ws_size,
                              hipStream_t stream) {
    const float* input = (const float*)d_in[0];   // right_input [B,C,H,W]
    const float* disp  = (const float*)d_in[1];   // disparity_samples [B,1,H,W]
    float* outp = (float*)d_out;

    const int grid = B * H * (C / CPB);           // 4*256*4 = 4096 blocks
    spatial_warp_kernel<<<grid, 512, 0, stream>>>(input, disp, outp);
}